// Round 6
// baseline (1068.042 us; speedup 1.0000x reference)
//
#include <hip/hip_runtime.h>

typedef unsigned short u16;
typedef __attribute__((ext_vector_type(8))) short bf16x8;   // 8 bf16 = 4 VGPRs
typedef __attribute__((ext_vector_type(4))) float f32x4;

__device__ __forceinline__ float bf2f(u16 u) {
    union { unsigned i; float f; } v; v.i = ((unsigned)u) << 16; return v.f;
}
__device__ __forceinline__ u16 f2bf(float f) {
    union { float f; unsigned i; } v; v.f = f;
    unsigned r = v.i + 0x7FFFu + ((v.i >> 16) & 1u);   // RNE
    return (u16)(r >> 16);
}

#define GL2LDS(g, l) __builtin_amdgcn_global_load_lds(                         \
    (const __attribute__((address_space(1))) void*)(g),                        \
    (__attribute__((address_space(3))) void*)(l), 16, 0, 0)

// ---------------------------------------------------------------------------
// gemm_bt: 128x128 tile, 2-barrier schedule (m97 structure). Unchanged core.
// Epilogues: 0 = +bias -> transposed bf16 [N][ldout]
//            1 = relu -> bf16 [M][ldout]
//            2 = bf16 partial, transposed [sk][NC][8192]
//            3 = appnp blend -> bf16 [N][ldout]
// ---------------------------------------------------------------------------
template<int EPI, int AFP32>
__global__ __launch_bounds__(256, 4)
void gemm_bt(const void* __restrict__ Ap, int lda,
             const u16* __restrict__ Bt, int ldb,
             int KB,
             void* __restrict__ outp,
             const void* __restrict__ aux,
             int ldout, int NC)
{
    __shared__ u16 aL[128 * 64];
    __shared__ u16 bL[128 * 64];

    const int t = threadIdx.x;
    const int wid = t >> 6, lane = t & 63;
    const int quad = lane >> 4, l15 = lane & 15, l7 = lane & 7;
    const int m0 = blockIdx.x * 128, n0 = blockIdx.y * 128;
    const int sk = blockIdx.z;
    const int k0 = sk * KB * 64;

    f32x4 acc[4][4];
    const f32x4 z4 = {0.f, 0.f, 0.f, 0.f};
#pragma unroll
    for (int i = 0; i < 4; ++i)
#pragma unroll
        for (int j = 0; j < 4; ++j) acc[i][j] = z4;

    const int wm = (wid >> 1) * 64, wn = (wid & 1) * 64;

    if (AFP32 == 0) {
        const char* pa[4]; const char* pb[4]; int lo[4];
#pragma unroll
        for (int i = 0; i < 4; ++i) {
            int flat = i * 4096 + wid * 1024 + lane * 16;
            int row  = flat >> 7;
            int csrc = ((flat >> 4) & 7) ^ (row & 7);
            pa[i] = (const char*)Ap + ((size_t)(m0 + row) * lda + k0) * 2 + csrc * 16;
            pb[i] = (const char*)Bt + ((size_t)(n0 + row) * ldb + k0) * 2 + csrc * 16;
            lo[i] = i * 4096 + wid * 1024;
        }
        for (int kb = 0; kb < KB; ++kb) {
#pragma unroll
            for (int i = 0; i < 4; ++i) GL2LDS(pa[i], (char*)aL + lo[i]);
#pragma unroll
            for (int i = 0; i < 4; ++i) GL2LDS(pb[i], (char*)bL + lo[i]);
#pragma unroll
            for (int i = 0; i < 4; ++i) { pa[i] += 128; pb[i] += 128; }
            __syncthreads();
#pragma unroll
            for (int ks = 0; ks < 2; ++ks) {
                const int cr = ((ks * 4 + quad) ^ l7) * 8;
                bf16x8 av[4], bv[4];
#pragma unroll
                for (int mi = 0; mi < 4; ++mi)
                    av[mi] = *(const bf16x8*)(aL + (wm + mi * 16 + l15) * 64 + cr);
#pragma unroll
                for (int ni = 0; ni < 4; ++ni)
                    bv[ni] = *(const bf16x8*)(bL + (wn + ni * 16 + l15) * 64 + cr);
#pragma unroll
                for (int mi = 0; mi < 4; ++mi)
#pragma unroll
                    for (int ni = 0; ni < 4; ++ni)
                        acc[mi][ni] = __builtin_amdgcn_mfma_f32_16x16x32_bf16(
                            av[mi], bv[ni], acc[mi][ni], 0, 0, 0);
            }
            __syncthreads();
        }
    } else {
        for (int kb = 0; kb < KB; ++kb) {
            const int kbase = k0 + kb * 64;
#pragma unroll
            for (int i = 0; i < 4; ++i) {
                int flat = i * 4096 + t * 16;
                int row  = flat >> 7;
                int col  = (flat & 127) >> 1;
                bf16x8 v = *(const bf16x8*)(Bt + (size_t)(n0 + row) * ldb + kbase + col);
                *(bf16x8*)(bL + row * 64 + col) = v;
            }
            const float* Af = (const float*)Ap;
#pragma unroll
            for (int j = 0; j < 8; ++j) {
                int f = j * 256 + t;
                int r = f >> 4, c = (f & 15) * 4;
                float4 v = *(const float4*)(Af + (size_t)(m0 + r) * lda + kbase + c);
                ushort4 o;
                o.x = f2bf(v.x); o.y = f2bf(v.y);
                o.z = f2bf(v.z); o.w = f2bf(v.w);
                *(ushort4*)(aL + r * 64 + c) = o;
            }
            __syncthreads();
#pragma unroll
            for (int ks = 0; ks < 2; ++ks) {
                const int cr = (ks * 4 + quad) * 8;
                bf16x8 av[4], bv[4];
#pragma unroll
                for (int mi = 0; mi < 4; ++mi)
                    av[mi] = *(const bf16x8*)(aL + (wm + mi * 16 + l15) * 64 + cr);
#pragma unroll
                for (int ni = 0; ni < 4; ++ni)
                    bv[ni] = *(const bf16x8*)(bL + (wn + ni * 16 + l15) * 64 + cr);
#pragma unroll
                for (int mi = 0; mi < 4; ++mi)
#pragma unroll
                    for (int ni = 0; ni < 4; ++ni)
                        acc[mi][ni] = __builtin_amdgcn_mfma_f32_16x16x32_bf16(
                            av[mi], bv[ni], acc[mi][ni], 0, 0, 0);
            }
            __syncthreads();
        }
    }

    if (EPI == 0) {
#pragma unroll
        for (int ni = 0; ni < 4; ++ni) {
            int n = n0 + wn + ni * 16 + l15;
            float bvv = ((const float*)aux)[n];
            u16* ob = (u16*)outp + (size_t)n * ldout;
#pragma unroll
            for (int mi = 0; mi < 4; ++mi) {
                int m = m0 + wm + mi * 16 + quad * 4;
                ushort4 o;
                o.x = f2bf(acc[mi][ni][0] + bvv);
                o.y = f2bf(acc[mi][ni][1] + bvv);
                o.z = f2bf(acc[mi][ni][2] + bvv);
                o.w = f2bf(acc[mi][ni][3] + bvv);
                *(ushort4*)(ob + m) = o;
            }
        }
    } else if (EPI == 2) {
#pragma unroll
        for (int ni = 0; ni < 4; ++ni) {
            int n = n0 + wn + ni * 16 + l15;
            u16* ob = (u16*)outp + ((size_t)(sk * NC + n)) * 8192;
#pragma unroll
            for (int mi = 0; mi < 4; ++mi) {
                int m = m0 + wm + mi * 16 + quad * 4;
                ushort4 o;
                o.x = f2bf(acc[mi][ni][0]);
                o.y = f2bf(acc[mi][ni][1]);
                o.z = f2bf(acc[mi][ni][2]);
                o.w = f2bf(acc[mi][ni][3]);
                *(ushort4*)(ob + m) = o;
            }
        }
    } else if (EPI == 3) {
#pragma unroll
        for (int ni = 0; ni < 4; ++ni) {
            int n = n0 + wn + ni * 16 + l15;
            const u16* zrow = (const u16*)aux + (size_t)n * 8192;
            u16* ob = (u16*)outp + (size_t)n * ldout;
#pragma unroll
            for (int mi = 0; mi < 4; ++mi) {
                int m = m0 + wm + mi * 16 + quad * 4;
                ushort4 z0 = *(const ushort4*)(zrow + m);
                ushort4 o;
                o.x = f2bf(0.9f * acc[mi][ni][0] + 0.1f * bf2f(z0.x));
                o.y = f2bf(0.9f * acc[mi][ni][1] + 0.1f * bf2f(z0.y));
                o.z = f2bf(0.9f * acc[mi][ni][2] + 0.1f * bf2f(z0.z));
                o.w = f2bf(0.9f * acc[mi][ni][3] + 0.1f * bf2f(z0.w));
                *(ushort4*)(ob + m) = o;
            }
        }
    } else {
        u16* ob = (u16*)outp;
#pragma unroll
        for (int mi = 0; mi < 4; ++mi) {
            int m = m0 + wm + mi * 16 + quad * 4;
#pragma unroll
            for (int ni = 0; ni < 4; ++ni) {
                int n = n0 + wn + ni * 16 + l15;
#pragma unroll
                for (int r = 0; r < 4; ++r)
                    ob[(size_t)(m + r) * ldout + n] = f2bf(fmaxf(acc[mi][ni][r], 0.0f));
            }
        }
    }
}

// ---------------------------------------------------------------------------
// gemm_bp: BM=128, BN=256, BK=64. 512 thr = 8 waves (2M x 4N), wave tile
// 64x64 (acc[4][4]). Triple-buffered LDS: A 3x16 KB @0, B 3x32 KB @49152 B
// = 144 KB -> 1 block/CU, 2 waves/SIMD. 2-tile prefetch lookahead: tile g
// issues A/B(g+2) into buf (g+2)%3 (whose reads completed before the
// end-of-(g-1) barrier). Counted vmcnt(6) per tile: steady-state FIFO =
// [A/B(g+1) 6, A/B(g+2) 6] -> vmcnt(6) drains exactly tile g+1's data.
// Tail: once prefetch stops (g+2 >= nt), drain with vmcnt(0) (fixes the
// gemm256 latent last-tile race). Same source-XOR-swizzle staging +
// chunk^(row&7) un-swizzle on ds_read as gemm_bt. Requires nt >= 3.
// Epilogue: bf16 partial, transposed [sk][NC][8192].
// ---------------------------------------------------------------------------
__global__ __launch_bounds__(512, 1)
void gemm_bp(const u16* __restrict__ A, int lda,
             const u16* __restrict__ Bt, int ldb,
             int nt,
             u16* __restrict__ part, int NC)
{
    __shared__ u16 lds[73728];             // 144 KB
    const int t = threadIdx.x;
    const int wid = t >> 6, lane = t & 63;
    const int quad = lane >> 4, l15 = lane & 15, l7 = lane & 7;
    const int wr = wid >> 2, wc = wid & 3;
    const int m0 = blockIdx.x * 128, n0 = blockIdx.y * 256;
    const int sk = blockIdx.z;
    const size_t k0 = (size_t)sk * nt * 64;

    f32x4 acc[4][4];
    const f32x4 z4 = {0.f, 0.f, 0.f, 0.f};
#pragma unroll
    for (int i = 0; i < 4; ++i)
#pragma unroll
        for (int j = 0; j < 4; ++j) acc[i][j] = z4;

    // staging: A 2 issues x 16 B/thread (16 KB), B 4 issues (32 KB).
    // dest lane-linear; source pre-swizzled chunk^(row&7).
    const char* pa[2]; int ua[2];
    const char* pb[4]; int ub[4];
#pragma unroll
    for (int j = 0; j < 2; ++j) {
        int p = j * 8192 + t * 16;
        int row = p >> 7;
        int csrc = ((p >> 4) & 7) ^ (row & 7);
        pa[j] = (const char*)A + ((size_t)(m0 + row) * lda + k0) * 2 + csrc * 16;
        ua[j] = j * 8192 + wid * 1024;
    }
#pragma unroll
    for (int j = 0; j < 4; ++j) {
        int p = j * 8192 + t * 16;
        int row = p >> 7;
        int csrc = ((p >> 4) & 7) ^ (row & 7);
        pb[j] = (const char*)Bt + ((size_t)(n0 + row) * ldb + k0) * 2 + csrc * 16;
        ub[j] = j * 8192 + wid * 1024;
    }
#define STGA_BP(d) { GL2LDS(pa[0], (char*)lds + (d) * 16384 + ua[0]);          \
                     GL2LDS(pa[1], (char*)lds + (d) * 16384 + ua[1]);          \
                     pa[0] += 128; pa[1] += 128; }
#define STGB_BP(d) { GL2LDS(pb[0], (char*)lds + 49152 + (d) * 32768 + ub[0]);  \
                     GL2LDS(pb[1], (char*)lds + 49152 + (d) * 32768 + ub[1]);  \
                     GL2LDS(pb[2], (char*)lds + 49152 + (d) * 32768 + ub[2]);  \
                     GL2LDS(pb[3], (char*)lds + 49152 + (d) * 32768 + ub[3]);  \
                     pb[0] += 128; pb[1] += 128; pb[2] += 128; pb[3] += 128; }

    // prologue: tiles 0,1. FIFO [A0 2, B0 4, A1 2, B1 4]; vmcnt(6) drains tile 0.
    STGA_BP(0); STGB_BP(0); STGA_BP(1); STGB_BP(1);
    asm volatile("s_waitcnt vmcnt(6)" ::: "memory");
    __builtin_amdgcn_s_barrier();

    const int aro = (wr * 64 + l15) * 128;     // A row byte offset (frag mi: +mi*2048)
    const int bro = (wc * 64 + l15) * 128;     // B row byte offset (frag ni: +ni*2048)
    const int cb0 = ((quad ^ l7) << 4);        // ks0 chunk bytes (un-swizzle)
    const int cb1 = (((4 + quad) ^ l7) << 4);  // ks1

    int d = 0, dn = 2;
    for (int g = 0; g < nt; ++g) {
        const char* Ab = (const char*)lds + d * 16384 + aro;
        const char* Bb = (const char*)lds + 49152 + d * 32768 + bro;
        bf16x8 av[4], bv[4];
        // ---- P0: ks0 ----
#pragma unroll
        for (int i = 0; i < 4; ++i) bv[i] = *(const bf16x8*)(Bb + i * 2048 + cb0);
#pragma unroll
        for (int i = 0; i < 4; ++i) av[i] = *(const bf16x8*)(Ab + i * 2048 + cb0);
        if (g + 2 < nt) { STGA_BP(dn); STGB_BP(dn); }
        __builtin_amdgcn_s_barrier();
        asm volatile("s_waitcnt lgkmcnt(0)" ::: "memory");
        __builtin_amdgcn_sched_barrier(0);
        __builtin_amdgcn_s_setprio(1);
#pragma unroll
        for (int mi = 0; mi < 4; ++mi)
#pragma unroll
            for (int ni = 0; ni < 4; ++ni)
                acc[mi][ni] = __builtin_amdgcn_mfma_f32_16x16x32_bf16(
                    av[mi], bv[ni], acc[mi][ni], 0, 0, 0);
        __builtin_amdgcn_s_setprio(0);
        __builtin_amdgcn_s_barrier();
        // ---- P1: ks1 ----
#pragma unroll
        for (int i = 0; i < 4; ++i) bv[i] = *(const bf16x8*)(Bb + i * 2048 + cb1);
#pragma unroll
        for (int i = 0; i < 4; ++i) av[i] = *(const bf16x8*)(Ab + i * 2048 + cb1);
        __builtin_amdgcn_s_barrier();
        asm volatile("s_waitcnt lgkmcnt(0)" ::: "memory");
        __builtin_amdgcn_sched_barrier(0);
        __builtin_amdgcn_s_setprio(1);
#pragma unroll
        for (int mi = 0; mi < 4; ++mi)
#pragma unroll
            for (int ni = 0; ni < 4; ++ni)
                acc[mi][ni] = __builtin_amdgcn_mfma_f32_16x16x32_bf16(
                    av[mi], bv[ni], acc[mi][ni], 0, 0, 0);
        __builtin_amdgcn_s_setprio(0);
        if (g + 2 < nt) { asm volatile("s_waitcnt vmcnt(6)" ::: "memory"); }
        else            { asm volatile("s_waitcnt vmcnt(0)" ::: "memory"); }
        __builtin_amdgcn_s_barrier();
        d  = (d  + 1 == 3) ? 0 : d  + 1;
        dn = (dn + 1 == 3) ? 0 : dn + 1;
    }

    // epilogue: bf16 partial, transposed [sk][NC][8192]
#pragma unroll
    for (int ni = 0; ni < 4; ++ni) {
        int n = n0 + wc * 64 + ni * 16 + l15;
        u16* ob = part + ((size_t)(sk * NC + n)) * 8192;
#pragma unroll
        for (int mi = 0; mi < 4; ++mi) {
            int m = m0 + wr * 64 + mi * 16 + quad * 4;
            ushort4 o;
            o.x = f2bf(acc[mi][ni][0]);
            o.y = f2bf(acc[mi][ni][1]);
            o.z = f2bf(acc[mi][ni][2]);
            o.w = f2bf(acc[mi][ni][3]);
            *(ushort4*)(ob + m) = o;
        }
    }
}
#undef STGA_BP
#undef STGB_BP

// ---------------------------------------------------------------------------
__global__ __launch_bounds__(256)
void cvt_f2b_k(const float* __restrict__ in, u16* __restrict__ out, long n4)
{
    long i = (long)blockIdx.x * 256 + threadIdx.x;
    long stride = (long)gridDim.x * 256;
    for (; i < n4; i += stride) {
        float4 v = ((const float4*)in)[i];
        ushort4 o;
        o.x = f2bf(v.x); o.y = f2bf(v.y); o.z = f2bf(v.z); o.w = f2bf(v.w);
        ((ushort4*)out)[i] = o;
    }
}

// ---------------------------------------------------------------------------
__global__ __launch_bounds__(256)
void transpose_cvt_k(const float* __restrict__ in, u16* __restrict__ out,
                     int R, int C)
{
    __shared__ u16 tile[32][33];
    int tx = threadIdx.x, ty = threadIdx.y;
    int x = blockIdx.x * 32 + tx;
    int y0 = blockIdx.y * 32 + ty;
#pragma unroll
    for (int j = 0; j < 32; j += 8)
        tile[ty + j][tx] = f2bf(in[(size_t)(y0 + j) * C + x]);
    __syncthreads();
    int x2 = blockIdx.y * 32 + tx;
    int y2 = blockIdx.x * 32 + ty;
#pragma unroll
    for (int j = 0; j < 32; j += 8)
        out[(size_t)(y2 + j) * R + x2] = tile[tx][ty + j];
}

// ---------------------------------------------------------------------------
template<int S>
__global__ __launch_bounds__(256)
void combine_bias_k(const u16* __restrict__ part, const float* __restrict__ bias,
                    u16* __restrict__ out, long NROW)
{
    const size_t Sz = (size_t)NROW * 8192;
    size_t e = ((size_t)blockIdx.x * 256 + threadIdx.x) * 4;
    int n = (int)(e >> 13);
    float b = bias[n];
    ushort4 p0 = *(const ushort4*)(part + e);
    float sx = bf2f(p0.x), sy = bf2f(p0.y), sz = bf2f(p0.z), sw = bf2f(p0.w);
#pragma unroll
    for (int i = 1; i < S; ++i) {
        ushort4 v = *(const ushort4*)(part + (size_t)i * Sz + e);
        sx += bf2f(v.x); sy += bf2f(v.y); sz += bf2f(v.z); sw += bf2f(v.w);
    }
    ushort4 o;
    o.x = f2bf(sx + b); o.y = f2bf(sy + b);
    o.z = f2bf(sz + b); o.w = f2bf(sw + b);
    *(ushort4*)(out + e) = o;
}

// ---------------------------------------------------------------------------
template<int S>
__global__ __launch_bounds__(256)
void combine_mlp_k(const u16* __restrict__ part, u16* __restrict__ y)
{
    __shared__ u16 L[64][68];
    const int t = threadIdx.x;
    const int mb = blockIdx.x * 64;
    const int nb = blockIdx.y * 64;
    const size_t Sz = (size_t)512 * 8192;
#pragma unroll
    for (int i = 0; i < 4; ++i) {
        int flat = i * 256 + t;
        int nl = flat >> 4;
        int mq = flat & 15;
        const u16* p0 = part + (size_t)(nb + nl) * 8192 + mb + mq * 4;
        ushort4 a4 = *(const ushort4*)p0;
        float ax = bf2f(a4.x), ay = bf2f(a4.y), az = bf2f(a4.z), aw = bf2f(a4.w);
#pragma unroll
        for (int s = 1; s < S; ++s) {
            ushort4 v = *(const ushort4*)(p0 + (size_t)s * Sz);
            ax += bf2f(v.x); ay += bf2f(v.y); az += bf2f(v.z); aw += bf2f(v.w);
        }
        ushort4 o;
        o.x = f2bf(fmaxf(ax, 0.f)); o.y = f2bf(fmaxf(ay, 0.f));
        o.z = f2bf(fmaxf(az, 0.f)); o.w = f2bf(fmaxf(aw, 0.f));
        *(ushort4*)&L[nl][mq * 4] = o;
    }
    __syncthreads();
#pragma unroll
    for (int i = 0; i < 4; ++i) {
        int flat = i * 256 + t;
        int ml  = flat >> 4;
        int nl4 = (flat & 15) * 4;
        ushort4 o;
        o.x = L[nl4 + 0][ml]; o.y = L[nl4 + 1][ml];
        o.z = L[nl4 + 2][ml]; o.w = L[nl4 + 3][ml];
        *(ushort4*)(y + (size_t)(mb + ml) * 512 + nb + nl4) = o;
    }
}

// ---------------------------------------------------------------------------
template<int S>
__global__ __launch_bounds__(256)
void combine_iter_k(const u16* __restrict__ part, const u16* __restrict__ z0T,
                    u16* __restrict__ zT)
{
    const size_t Sz = (size_t)256 * 8192;
    size_t e = ((size_t)blockIdx.x * 256 + threadIdx.x) * 4;
    ushort4 p0 = *(const ushort4*)(part + e);
    float ax = bf2f(p0.x), ay = bf2f(p0.y), az = bf2f(p0.z), aw = bf2f(p0.w);
#pragma unroll
    for (int s = 1; s < S; ++s) {
        ushort4 v = *(const ushort4*)(part + (size_t)s * Sz + e);
        ax += bf2f(v.x); ay += bf2f(v.y); az += bf2f(v.z); aw += bf2f(v.w);
    }
    ushort4 z0 = *(const ushort4*)(z0T + e);
    ushort4 o;
    o.x = f2bf(0.9f * ax + 0.1f * bf2f(z0.x));
    o.y = f2bf(0.9f * ay + 0.1f * bf2f(z0.y));
    o.z = f2bf(0.9f * az + 0.1f * bf2f(z0.z));
    o.w = f2bf(0.9f * aw + 0.1f * bf2f(z0.w));
    *(ushort4*)(zT + e) = o;
}

// ---------------------------------------------------------------------------
__global__ __launch_bounds__(256)
void softmax_k(const u16* __restrict__ zT, float* __restrict__ out)
{
    __shared__ u16 L[64][260];
    const int t = threadIdx.x;
    const int m0 = blockIdx.x * 64;
    const int tx = t & 15, ty = t >> 4;
#pragma unroll
    for (int i = 0; i < 16; ++i) {
        int n = i * 16 + ty;
        ushort4 v = *(const ushort4*)(zT + (size_t)n * 8192 + m0 + tx * 4);
        L[tx * 4 + 0][n] = v.x; L[tx * 4 + 1][n] = v.y;
        L[tx * 4 + 2][n] = v.z; L[tx * 4 + 3][n] = v.w;
    }
    __syncthreads();
    const int wid = t >> 6, lane = t & 63;
    for (int r = 0; r < 16; ++r) {
        int mm = wid * 16 + r;
        ushort4 u = *(const ushort4*)(&L[mm][lane * 4]);
        float f0 = bf2f(u.x), f1 = bf2f(u.y), f2 = bf2f(u.z), f3 = bf2f(u.w);
        float mx = fmaxf(fmaxf(f0, f1), fmaxf(f2, f3));
#pragma unroll
        for (int off = 32; off > 0; off >>= 1) mx = fmaxf(mx, __shfl_xor(mx, off));
        float e0 = __expf(f0 - mx), e1 = __expf(f1 - mx);
        float e2 = __expf(f2 - mx), e3 = __expf(f3 - mx);
        float s = e0 + e1 + e2 + e3;
#pragma unroll
        for (int off = 32; off > 0; off >>= 1) s += __shfl_xor(s, off);
        float inv = 1.0f / s;
        float4 o;
        o.x = e0 * inv; o.y = e1 * inv; o.z = e2 * inv; o.w = e3 * inv;
        *(float4*)(out + (size_t)(m0 + mm) * 256 + lane * 4) = o;
    }
}

// ---------------------------------------------------------------------------
extern "C" void kernel_launch(void* const* d_in, const int* in_sizes, int n_in,
                              void* d_out, int out_size, void* d_ws, size_t ws_size,
                              hipStream_t stream)
{
    const float* features = (const float*)d_in[0];   // [8192][512]
    const float* fltr     = (const float*)d_in[1];   // [8192][8192]
    const float* W0       = (const float*)d_in[2];   // [512][512]
    const float* b0       = (const float*)d_in[3];   // [512]
    const float* W1       = (const float*)d_in[4];   // [512][512]
    const float* b1       = (const float*)d_in[5];   // [512]
    const float* Wo       = (const float*)d_in[6];   // [512][256]
    const float* bo       = (const float*)d_in[7];   // [256]

    dim3 tb(32, 8);

    // ---- base ws layout (~71 MB; part bf16) ----
    char* p = (char*)d_ws;
    u16* fB  = (u16*)p;  p += (size_t)8192 * 512 * 2;
    u16* W0T = (u16*)p;  p += (size_t)512 * 512 * 2;
    u16* W1T = (u16*)p;  p += (size_t)512 * 512 * 2;
    u16* WoT = (u16*)p;  p += (size_t)256 * 512 * 2;
    u16* z0T = (u16*)p;  p += (size_t)256 * 8192 * 2;
    u16* zA  = (u16*)p;  p += (size_t)256 * 8192 * 2;
    u16* zB  = (u16*)p;  p += (size_t)256 * 8192 * 2;
    u16* tT  = (u16*)p;  p += (size_t)512 * 8192 * 2;
    u16* y   = (u16*)p;  p += (size_t)8192 * 512 * 2;
    u16* part = (u16*)p; p += (size_t)4 * 512 * 8192 * 2;   // 33.6 MB reserve
    size_t base_need = (size_t)(p - (char*)d_ws);
    u16* fltrB = (u16*)p;                             // +134.2 MB (full tier)
    size_t full_need = base_need + (size_t)8192 * 8192 * 2;

    if (ws_size >= full_need) {
        // ================= FULL TIER =================
        cvt_f2b_k<<<2048, 256, 0, stream>>>(fltr, fltrB, (long)8192 * 8192 / 4);
        cvt_f2b_k<<<512, 256, 0, stream>>>(features, fB, (long)8192 * 512 / 4);
        transpose_cvt_k<<<dim3(16, 16), tb, 0, stream>>>(W0, W0T, 512, 512);
        transpose_cvt_k<<<dim3(16, 16), tb, 0, stream>>>(W1, W1T, 512, 512);
        transpose_cvt_k<<<dim3(8, 16),  tb, 0, stream>>>(Wo, WoT, 512, 256);

        // t0 = (features @ W0 + b0)^T  — direct, sk=1, 256 blocks
        gemm_bt<0, 0><<<dim3(64, 4, 1), 256, 0, stream>>>(fB, 512, W0T, 512, 8,
                                                          tT, b0, 8192, 0);
        // y1 = relu(fltr @ t0) — 128x256 3-buf pipeline, sk=2, 256 blocks, nt=64
        gemm_bp<<<dim3(64, 2, 2), 512, 0, stream>>>(fltrB, 8192, tT, 8192, 64,
                                                    part, 512);
        combine_mlp_k<2><<<dim3(128, 8), 256, 0, stream>>>(part, y);
        // t1 = (y1 @ W1 + b1)^T     — direct, sk=1
        gemm_bt<0, 0><<<dim3(64, 4, 1), 256, 0, stream>>>(y, 512, W1T, 512, 8,
                                                          tT, b1, 8192, 0);
        // y2 = relu(fltr @ t1)
        gemm_bp<<<dim3(64, 2, 2), 512, 0, stream>>>(fltrB, 8192, tT, 8192, 64,
                                                    part, 512);
        combine_mlp_k<2><<<dim3(128, 8), 256, 0, stream>>>(part, y);
        // z0 = (y2 @ Wo + bo)^T     — direct, sk=1, 128 blocks
        gemm_bt<0, 0><<<dim3(64, 2, 1), 256, 0, stream>>>(y, 512, WoT, 512, 8,
                                                          z0T, bo, 8192, 0);
        // 10x: z <- 0.9*fltr@z + 0.1*z0 — sk=4, 256 blocks, nt=32
        const u16* src = z0T;
        for (int it = 0; it < 10; ++it) {
            u16* dst = (it & 1) ? zB : zA;
            gemm_bp<<<dim3(64, 1, 4), 512, 0, stream>>>(fltrB, 8192, src, 8192,
                                                        32, part, 256);
            combine_iter_k<4><<<2048, 256, 0, stream>>>(part, z0T, dst);
            src = dst;
        }
        softmax_k<<<128, 256, 0, stream>>>(src, (float*)d_out);
    } else if (ws_size >= base_need) {
        // ================= MIDDLE TIER (fltr stays fp32) =================
        cvt_f2b_k<<<512, 256, 0, stream>>>(features, fB, (long)8192 * 512 / 4);
        transpose_cvt_k<<<dim3(16, 16), tb, 0, stream>>>(W0, W0T, 512, 512);
        transpose_cvt_k<<<dim3(16, 16), tb, 0, stream>>>(W1, W1T, 512, 512);
        transpose_cvt_k<<<dim3(8, 16),  tb, 0, stream>>>(Wo, WoT, 512, 256);

        gemm_bt<2, 0><<<dim3(64, 4, 2), 256, 0, stream>>>(fB, 512, W0T, 512, 4,
                                                          part, nullptr, 0, 512);
        combine_bias_k<2><<<4096, 256, 0, stream>>>(part, b0, tT, 512);
        gemm_bt<2, 1><<<dim3(64, 4, 4), 256, 0, stream>>>(fltr, 8192, tT, 8192,
                                                          32, part, nullptr, 0, 512);
        combine_mlp_k<4><<<dim3(128, 8), 256, 0, stream>>>(part, y);
        gemm_bt<2, 0><<<dim3(64, 4, 2), 256, 0, stream>>>(y, 512, W1T, 512, 4,
                                                          part, nullptr, 0, 512);
        combine_bias_k<2><<<4096, 256, 0, stream>>>(part, b1, tT, 512);
        gemm_bt<2, 1><<<dim3(64, 4, 4), 256, 0, stream>>>(fltr, 8192, tT, 8192,
                                                          32, part, nullptr, 0, 512);
        combine_mlp_k<4><<<dim3(128, 8), 256, 0, stream>>>(part, y);
        gemm_bt<2, 0><<<dim3(64, 2, 4), 256, 0, stream>>>(y, 512, WoT, 512, 2,
                                                          part, nullptr, 0, 256);
        combine_bias_k<4><<<2048, 256, 0, stream>>>(part, bo, z0T, 256);
        const u16* src = z0T;
        for (int it = 0; it < 10; ++it) {
            u16* dst = (it & 1) ? zB : zA;
            gemm_bt<2, 1><<<dim3(64, 2, 8), 256, 0, stream>>>(fltr, 8192, src,
                                                              8192, 16, part,
                                                              nullptr, 0, 256);
            combine_iter_k<8><<<2048, 256, 0, stream>>>(part, z0T, dst);
            src = dst;
        }
        softmax_k<<<128, 256, 0, stream>>>(src, (float*)d_out);
    } else {
        // ================= FALLBACK (21.25 MB) =================
        char* w = (char*)d_ws;
        u16* fW0T = (u16*)w;  w += (size_t)512 * 512 * 2;
        u16* fW1T = (u16*)w;  w += (size_t)512 * 512 * 2;
        u16* fWoT = (u16*)w;  w += (size_t)256 * 512 * 2;
        u16* fz0T = (u16*)w;  w += (size_t)256 * 8192 * 2;
        char* rb = w;
        u16* ftT = (u16*)rb;
        u16* fy  = (u16*)(rb + (size_t)512 * 8192 * 2);
        u16* fzA = (u16*)rb;
        u16* fzB = (u16*)(rb + (size_t)256 * 8192 * 2);

        transpose_cvt_k<<<dim3(16, 16), tb, 0, stream>>>(W0, fW0T, 512, 512);
        transpose_cvt_k<<<dim3(16, 16), tb, 0, stream>>>(W1, fW1T, 512, 512);
        transpose_cvt_k<<<dim3(8, 16),  tb, 0, stream>>>(Wo, fWoT, 512, 256);
        gemm_bt<0, 1><<<dim3(64, 4), 256, 0, stream>>>(features, 512, fW0T, 512, 8,
                                                       ftT, b0, 8192, 0);
        gemm_bt<1, 1><<<dim3(64, 4), 256, 0, stream>>>(fltr, 8192, ftT, 8192, 128,
                                                       fy, nullptr, 512, 0);
        gemm_bt<0, 0><<<dim3(64, 4), 256, 0, stream>>>(fy, 512, fW1T, 512, 8,
                                                       ftT, b1, 8192, 0);
        gemm_bt<1, 1><<<dim3(64, 4), 256, 0, stream>>>(fltr, 8192, ftT, 8192, 128,
                                                       fy, nullptr, 512, 0);
        gemm_bt<0, 0><<<dim3(64, 2), 256, 0, stream>>>(fy, 512, fWoT, 512, 8,
                                                       fz0T, bo, 8192, 0);
        const u16* src = fz0T;
        for (int it = 0; it < 10; ++it) {
            u16* dst = (it & 1) ? fzB : fzA;
            gemm_bt<3, 1><<<dim3(64, 2), 256, 0, stream>>>(fltr, 8192, src, 8192,
                                                           128, dst, fz0T, 8192, 0);
            src = dst;
        }
        softmax_k<<<128, 256, 0, stream>>>(src, (float*)d_out);
    }
}

// Round 7
// 1065.486 us; speedup vs baseline: 1.0024x; 1.0024x over previous
//
#include <hip/hip_runtime.h>

typedef unsigned short u16;
typedef __attribute__((ext_vector_type(8))) short bf16x8;   // 8 bf16 = 4 VGPRs
typedef __attribute__((ext_vector_type(4))) float f32x4;

__device__ __forceinline__ float bf2f(u16 u) {
    union { unsigned i; float f; } v; v.i = ((unsigned)u) << 16; return v.f;
}
__device__ __forceinline__ u16 f2bf(float f) {
    union { float f; unsigned i; } v; v.f = f;
    unsigned r = v.i + 0x7FFFu + ((v.i >> 16) & 1u);   // RNE
    return (u16)(r >> 16);
}

#define GL2LDS(g, l) __builtin_amdgcn_global_load_lds(                         \
    (const __attribute__((address_space(1))) void*)(g),                        \
    (__attribute__((address_space(3))) void*)(l), 16, 0, 0)

// ---------------------------------------------------------------------------
// gemm_bt: 128x128 tile, 2-barrier schedule (m97 structure). Unchanged core.
// Epilogues: 0 = +bias -> transposed bf16 [N][ldout]
//            1 = relu -> bf16 [M][ldout]
//            2 = bf16 partial, transposed [sk][NC][8192]
//            3 = appnp blend -> bf16 [N][ldout]
// ---------------------------------------------------------------------------
template<int EPI, int AFP32>
__global__ __launch_bounds__(256, 4)
void gemm_bt(const void* __restrict__ Ap, int lda,
             const u16* __restrict__ Bt, int ldb,
             int KB,
             void* __restrict__ outp,
             const void* __restrict__ aux,
             int ldout, int NC)
{
    __shared__ u16 aL[128 * 64];
    __shared__ u16 bL[128 * 64];

    const int t = threadIdx.x;
    const int wid = t >> 6, lane = t & 63;
    const int quad = lane >> 4, l15 = lane & 15, l7 = lane & 7;
    const int m0 = blockIdx.x * 128, n0 = blockIdx.y * 128;
    const int sk = blockIdx.z;
    const int k0 = sk * KB * 64;

    f32x4 acc[4][4];
    const f32x4 z4 = {0.f, 0.f, 0.f, 0.f};
#pragma unroll
    for (int i = 0; i < 4; ++i)
#pragma unroll
        for (int j = 0; j < 4; ++j) acc[i][j] = z4;

    const int wm = (wid >> 1) * 64, wn = (wid & 1) * 64;

    if (AFP32 == 0) {
        const char* pa[4]; const char* pb[4]; int lo[4];
#pragma unroll
        for (int i = 0; i < 4; ++i) {
            int flat = i * 4096 + wid * 1024 + lane * 16;
            int row  = flat >> 7;
            int csrc = ((flat >> 4) & 7) ^ (row & 7);
            pa[i] = (const char*)Ap + ((size_t)(m0 + row) * lda + k0) * 2 + csrc * 16;
            pb[i] = (const char*)Bt + ((size_t)(n0 + row) * ldb + k0) * 2 + csrc * 16;
            lo[i] = i * 4096 + wid * 1024;
        }
        for (int kb = 0; kb < KB; ++kb) {
#pragma unroll
            for (int i = 0; i < 4; ++i) GL2LDS(pa[i], (char*)aL + lo[i]);
#pragma unroll
            for (int i = 0; i < 4; ++i) GL2LDS(pb[i], (char*)bL + lo[i]);
#pragma unroll
            for (int i = 0; i < 4; ++i) { pa[i] += 128; pb[i] += 128; }
            __syncthreads();
#pragma unroll
            for (int ks = 0; ks < 2; ++ks) {
                const int cr = ((ks * 4 + quad) ^ l7) * 8;
                bf16x8 av[4], bv[4];
#pragma unroll
                for (int mi = 0; mi < 4; ++mi)
                    av[mi] = *(const bf16x8*)(aL + (wm + mi * 16 + l15) * 64 + cr);
#pragma unroll
                for (int ni = 0; ni < 4; ++ni)
                    bv[ni] = *(const bf16x8*)(bL + (wn + ni * 16 + l15) * 64 + cr);
#pragma unroll
                for (int mi = 0; mi < 4; ++mi)
#pragma unroll
                    for (int ni = 0; ni < 4; ++ni)
                        acc[mi][ni] = __builtin_amdgcn_mfma_f32_16x16x32_bf16(
                            av[mi], bv[ni], acc[mi][ni], 0, 0, 0);
            }
            __syncthreads();
        }
    } else {
        for (int kb = 0; kb < KB; ++kb) {
            const int kbase = k0 + kb * 64;
#pragma unroll
            for (int i = 0; i < 4; ++i) {
                int flat = i * 4096 + t * 16;
                int row  = flat >> 7;
                int col  = (flat & 127) >> 1;
                bf16x8 v = *(const bf16x8*)(Bt + (size_t)(n0 + row) * ldb + kbase + col);
                *(bf16x8*)(bL + row * 64 + col) = v;
            }
            const float* Af = (const float*)Ap;
#pragma unroll
            for (int j = 0; j < 8; ++j) {
                int f = j * 256 + t;
                int r = f >> 4, c = (f & 15) * 4;
                float4 v = *(const float4*)(Af + (size_t)(m0 + r) * lda + kbase + c);
                ushort4 o;
                o.x = f2bf(v.x); o.y = f2bf(v.y);
                o.z = f2bf(v.z); o.w = f2bf(v.w);
                *(ushort4*)(aL + r * 64 + c) = o;
            }
            __syncthreads();
#pragma unroll
            for (int ks = 0; ks < 2; ++ks) {
                const int cr = (ks * 4 + quad) * 8;
                bf16x8 av[4], bv[4];
#pragma unroll
                for (int mi = 0; mi < 4; ++mi)
                    av[mi] = *(const bf16x8*)(aL + (wm + mi * 16 + l15) * 64 + cr);
#pragma unroll
                for (int ni = 0; ni < 4; ++ni)
                    bv[ni] = *(const bf16x8*)(bL + (wn + ni * 16 + l15) * 64 + cr);
#pragma unroll
                for (int mi = 0; mi < 4; ++mi)
#pragma unroll
                    for (int ni = 0; ni < 4; ++ni)
                        acc[mi][ni] = __builtin_amdgcn_mfma_f32_16x16x32_bf16(
                            av[mi], bv[ni], acc[mi][ni], 0, 0, 0);
            }
            __syncthreads();
        }
    }

    if (EPI == 0) {
#pragma unroll
        for (int ni = 0; ni < 4; ++ni) {
            int n = n0 + wn + ni * 16 + l15;
            float bvv = ((const float*)aux)[n];
            u16* ob = (u16*)outp + (size_t)n * ldout;
#pragma unroll
            for (int mi = 0; mi < 4; ++mi) {
                int m = m0 + wm + mi * 16 + quad * 4;
                ushort4 o;
                o.x = f2bf(acc[mi][ni][0] + bvv);
                o.y = f2bf(acc[mi][ni][1] + bvv);
                o.z = f2bf(acc[mi][ni][2] + bvv);
                o.w = f2bf(acc[mi][ni][3] + bvv);
                *(ushort4*)(ob + m) = o;
            }
        }
    } else if (EPI == 2) {
#pragma unroll
        for (int ni = 0; ni < 4; ++ni) {
            int n = n0 + wn + ni * 16 + l15;
            u16* ob = (u16*)outp + ((size_t)(sk * NC + n)) * 8192;
#pragma unroll
            for (int mi = 0; mi < 4; ++mi) {
                int m = m0 + wm + mi * 16 + quad * 4;
                ushort4 o;
                o.x = f2bf(acc[mi][ni][0]);
                o.y = f2bf(acc[mi][ni][1]);
                o.z = f2bf(acc[mi][ni][2]);
                o.w = f2bf(acc[mi][ni][3]);
                *(ushort4*)(ob + m) = o;
            }
        }
    } else if (EPI == 3) {
#pragma unroll
        for (int ni = 0; ni < 4; ++ni) {
            int n = n0 + wn + ni * 16 + l15;
            const u16* zrow = (const u16*)aux + (size_t)n * 8192;
            u16* ob = (u16*)outp + (size_t)n * ldout;
#pragma unroll
            for (int mi = 0; mi < 4; ++mi) {
                int m = m0 + wm + mi * 16 + quad * 4;
                ushort4 z0 = *(const ushort4*)(zrow + m);
                ushort4 o;
                o.x = f2bf(0.9f * acc[mi][ni][0] + 0.1f * bf2f(z0.x));
                o.y = f2bf(0.9f * acc[mi][ni][1] + 0.1f * bf2f(z0.y));
                o.z = f2bf(0.9f * acc[mi][ni][2] + 0.1f * bf2f(z0.z));
                o.w = f2bf(0.9f * acc[mi][ni][3] + 0.1f * bf2f(z0.w));
                *(ushort4*)(ob + m) = o;
            }
        }
    } else {
        u16* ob = (u16*)outp;
#pragma unroll
        for (int mi = 0; mi < 4; ++mi) {
            int m = m0 + wm + mi * 16 + quad * 4;
#pragma unroll
            for (int ni = 0; ni < 4; ++ni) {
                int n = n0 + wn + ni * 16 + l15;
#pragma unroll
                for (int r = 0; r < 4; ++r)
                    ob[(size_t)(m + r) * ldout + n] = f2bf(fmaxf(acc[mi][ni][r], 0.0f));
            }
        }
    }
}

// ---------------------------------------------------------------------------
// gemm256: 256x256 tile, BK=64, 512 thr = 8 waves (2M x 4N), wave tile 128x64.
// 4-phase schedule, double-buffered LDS (128 KB). R7 changes vs R5:
//  - both A(g+1) halves issued at P0 (one phase more latency cover; ledger:
//    end-of-tile outstanding = B(g+1)4 + A(g+1)4 + B(g+2)4 -> vmcnt(4)
//    drains A/B(g+1), leaves B(g+2)).
//  - tail fix: once prefetch stops (g+2 >= nt), end-of-tile drains vmcnt(0)
//    so A(nt-1) is guaranteed landed before the last tile reads it.
// B(g+2) stays at P3: B buf d writes must follow all waves' P2 reads, which
// are only guaranteed drained at P2's second barrier.
// Epilogue: bf16 partial, transposed [sk][NC][8192].
// ---------------------------------------------------------------------------
#define PHASE_MFMA(MH)                                                        \
    asm volatile("s_waitcnt lgkmcnt(0)" ::: "memory");                        \
    __builtin_amdgcn_sched_barrier(0);                                        \
    __builtin_amdgcn_s_setprio(1);                                            \
    _Pragma("unroll")                                                         \
    for (int mi = 0; mi < 4; ++mi)                                            \
        _Pragma("unroll")                                                     \
        for (int ni = 0; ni < 4; ++ni)                                        \
            acc[(MH) * 4 + mi][ni] = __builtin_amdgcn_mfma_f32_16x16x32_bf16( \
                av[mi], bv[ni], acc[(MH) * 4 + mi][ni], 0, 0, 0);             \
    __builtin_amdgcn_s_setprio(0);

__global__ __launch_bounds__(512, 2)
void gemm256(const u16* __restrict__ A, int lda,
             const u16* __restrict__ Bt, int ldb,
             int nt,                        // K-tiles of 64 per split (>= 2)
             u16* __restrict__ part, int NC)
{
    __shared__ u16 lds[65536];             // 128 KB: A [0,64K), B [64K,128K)
    const int t = threadIdx.x;
    const int wid = t >> 6, lane = t & 63;
    const int quad = lane >> 4, l15 = lane & 15, l7 = lane & 7;
    const int wr = wid >> 2, wc = wid & 3;
    const int m0 = blockIdx.x * 256, n0 = blockIdx.y * 256;
    const int sk = blockIdx.z;
    const size_t k0 = (size_t)sk * nt * 64;

    f32x4 acc[8][4];
    const f32x4 z4 = {0.f, 0.f, 0.f, 0.f};
#pragma unroll
    for (int i = 0; i < 8; ++i)
#pragma unroll
        for (int j = 0; j < 4; ++j) acc[i][j] = z4;

    // staging pointers: p = byte pos in 16 KB half-tile (lane-linear dest);
    // source pre-swizzled: 16B chunk csrc = chunk ^ (row & 7)
    const char* pa[2][2]; const char* pb[2][2]; int uo[2][2];
#pragma unroll
    for (int h = 0; h < 2; ++h)
#pragma unroll
        for (int j = 0; j < 2; ++j) {
            int p = j * 8192 + wid * 1024 + lane * 16;
            int row = p >> 7;
            int csrc = ((p >> 4) & 7) ^ (row & 7);
            pa[h][j] = (const char*)A +
                ((size_t)(m0 + h * 128 + row) * lda + k0) * 2 + csrc * 16;
            pb[h][j] = (const char*)Bt +
                ((size_t)(n0 + h * 128 + row) * ldb + k0) * 2 + csrc * 16;
            uo[h][j] = h * 16384 + j * 8192 + wid * 1024;   // wave-uniform dest
        }
#define STGA(h, d) { GL2LDS(pa[h][0], (char*)lds + (d) * 32768 + uo[h][0]);    \
                     GL2LDS(pa[h][1], (char*)lds + (d) * 32768 + uo[h][1]);    \
                     pa[h][0] += 128; pa[h][1] += 128; }
#define STGB(h, d) { GL2LDS(pb[h][0], (char*)lds + 65536 + (d) * 32768 + uo[h][0]); \
                     GL2LDS(pb[h][1], (char*)lds + 65536 + (d) * 32768 + uo[h][1]); \
                     pb[h][0] += 128; pb[h][1] += 128; }

    // prologue: K-tiles 0 and 1
    STGA(0, 0); STGA(1, 0); STGB(0, 0); STGB(1, 0);
    STGA(0, 1); STGA(1, 1); STGB(0, 1); STGB(1, 1);
    asm volatile("s_waitcnt vmcnt(8)" ::: "memory");
    __builtin_amdgcn_s_barrier();

    const int cb0 = ((quad ^ l7) << 4);            // ks0 col bytes (unswizzle)
    const int cb1 = (((4 + quad) ^ l7) << 4);      // ks1
    const int aro = l15 * 128;
    const int bro = ((wc & 1) * 64 + l15) * 128;

    for (int g = 0; g < nt; ++g) {
        const int d = g & 1;
        const char* Ab = (const char*)lds + d * 32768 + wr * 16384 + aro;
        const char* Bb = (const char*)lds + 65536 + d * 32768 + (wc >> 1) * 16384 + bro;
        bf16x8 av[4], bv[4];
        // ---- P0: ks0, mh0 ----
#pragma unroll
        for (int i = 0; i < 4; ++i) bv[i] = *(const bf16x8*)(Bb + i * 2048 + cb0);
#pragma unroll
        for (int i = 0; i < 4; ++i) av[i] = *(const bf16x8*)(Ab + i * 2048 + cb0);
        if (g >= 1 && g + 1 < nt) { STGA(0, d ^ 1); STGA(1, d ^ 1); }
        __builtin_amdgcn_s_barrier();
        PHASE_MFMA(0)
        __builtin_amdgcn_s_barrier();
        // ---- P1: ks0, mh1 ----
#pragma unroll
        for (int i = 0; i < 4; ++i) av[i] = *(const bf16x8*)(Ab + (4 + i) * 2048 + cb0);
        __builtin_amdgcn_s_barrier();
        PHASE_MFMA(1)
        __builtin_amdgcn_s_barrier();
        // ---- P2: ks1, mh0 ----
#pragma unroll
        for (int i = 0; i < 4; ++i) bv[i] = *(const bf16x8*)(Bb + i * 2048 + cb1);
#pragma unroll
        for (int i = 0; i < 4; ++i) av[i] = *(const bf16x8*)(Ab + i * 2048 + cb1);
        __builtin_amdgcn_s_barrier();
        PHASE_MFMA(0)
        __builtin_amdgcn_s_barrier();
        // ---- P3: ks1, mh1 ----
#pragma unroll
        for (int i = 0; i < 4; ++i) av[i] = *(const bf16x8*)(Ab + (4 + i) * 2048 + cb1);
        if (g + 2 < nt) { STGB(0, d); STGB(1, d); }
        __builtin_amdgcn_s_barrier();
        PHASE_MFMA(1)
        if (g + 2 < nt) { asm volatile("s_waitcnt vmcnt(4)" ::: "memory"); }
        else            { asm volatile("s_waitcnt vmcnt(0)" ::: "memory"); }
        __builtin_amdgcn_s_barrier();
    }

    // epilogue: bf16 partial, transposed [sk][NC][8192]
#pragma unroll
    for (int ni = 0; ni < 4; ++ni) {
        int n = n0 + wc * 64 + ni * 16 + l15;
        u16* ob = part + ((size_t)(sk * NC + n)) * 8192;
#pragma unroll
        for (int mi = 0; mi < 8; ++mi) {
            int m = m0 + wr * 128 + mi * 16 + quad * 4;
            ushort4 o;
            o.x = f2bf(acc[mi][ni][0]);
            o.y = f2bf(acc[mi][ni][1]);
            o.z = f2bf(acc[mi][ni][2]);
            o.w = f2bf(acc[mi][ni][3]);
            *(ushort4*)(ob + m) = o;
        }
    }
}
#undef STGA
#undef STGB

// ---------------------------------------------------------------------------
__global__ __launch_bounds__(256)
void cvt_f2b_k(const float* __restrict__ in, u16* __restrict__ out, long n4)
{
    long i = (long)blockIdx.x * 256 + threadIdx.x;
    long stride = (long)gridDim.x * 256;
    for (; i < n4; i += stride) {
        float4 v = ((const float4*)in)[i];
        ushort4 o;
        o.x = f2bf(v.x); o.y = f2bf(v.y); o.z = f2bf(v.z); o.w = f2bf(v.w);
        ((ushort4*)out)[i] = o;
    }
}

// ---------------------------------------------------------------------------
__global__ __launch_bounds__(256)
void transpose_cvt_k(const float* __restrict__ in, u16* __restrict__ out,
                     int R, int C)
{
    __shared__ u16 tile[32][33];
    int tx = threadIdx.x, ty = threadIdx.y;
    int x = blockIdx.x * 32 + tx;
    int y0 = blockIdx.y * 32 + ty;
#pragma unroll
    for (int j = 0; j < 32; j += 8)
        tile[ty + j][tx] = f2bf(in[(size_t)(y0 + j) * C + x]);
    __syncthreads();
    int x2 = blockIdx.y * 32 + tx;
    int y2 = blockIdx.x * 32 + ty;
#pragma unroll
    for (int j = 0; j < 32; j += 8)
        out[(size_t)(y2 + j) * R + x2] = tile[tx][ty + j];
}

// ---------------------------------------------------------------------------
template<int S>
__global__ __launch_bounds__(256)
void combine_bias_k(const u16* __restrict__ part, const float* __restrict__ bias,
                    u16* __restrict__ out, long NROW)
{
    const size_t Sz = (size_t)NROW * 8192;
    size_t e = ((size_t)blockIdx.x * 256 + threadIdx.x) * 4;
    int n = (int)(e >> 13);
    float b = bias[n];
    ushort4 p0 = *(const ushort4*)(part + e);
    float sx = bf2f(p0.x), sy = bf2f(p0.y), sz = bf2f(p0.z), sw = bf2f(p0.w);
#pragma unroll
    for (int i = 1; i < S; ++i) {
        ushort4 v = *(const ushort4*)(part + (size_t)i * Sz + e);
        sx += bf2f(v.x); sy += bf2f(v.y); sz += bf2f(v.z); sw += bf2f(v.w);
    }
    ushort4 o;
    o.x = f2bf(sx + b); o.y = f2bf(sy + b);
    o.z = f2bf(sz + b); o.w = f2bf(sw + b);
    *(ushort4*)(out + e) = o;
}

// ---------------------------------------------------------------------------
template<int S>
__global__ __launch_bounds__(256)
void combine_mlp_k(const u16* __restrict__ part, u16* __restrict__ y)
{
    __shared__ u16 L[64][68];
    const int t = threadIdx.x;
    const int mb = blockIdx.x * 64;
    const int nb = blockIdx.y * 64;
    const size_t Sz = (size_t)512 * 8192;
#pragma unroll
    for (int i = 0; i < 4; ++i) {
        int flat = i * 256 + t;
        int nl = flat >> 4;
        int mq = flat & 15;
        const u16* p0 = part + (size_t)(nb + nl) * 8192 + mb + mq * 4;
        ushort4 a4 = *(const ushort4*)p0;
        float ax = bf2f(a4.x), ay = bf2f(a4.y), az = bf2f(a4.z), aw = bf2f(a4.w);
#pragma unroll
        for (int s = 1; s < S; ++s) {
            ushort4 v = *(const ushort4*)(p0 + (size_t)s * Sz);
            ax += bf2f(v.x); ay += bf2f(v.y); az += bf2f(v.z); aw += bf2f(v.w);
        }
        ushort4 o;
        o.x = f2bf(fmaxf(ax, 0.f)); o.y = f2bf(fmaxf(ay, 0.f));
        o.z = f2bf(fmaxf(az, 0.f)); o.w = f2bf(fmaxf(aw, 0.f));
        *(ushort4*)&L[nl][mq * 4] = o;
    }
    __syncthreads();
#pragma unroll
    for (int i = 0; i < 4; ++i) {
        int flat = i * 256 + t;
        int ml  = flat >> 4;
        int nl4 = (flat & 15) * 4;
        ushort4 o;
        o.x = L[nl4 + 0][ml]; o.y = L[nl4 + 1][ml];
        o.z = L[nl4 + 2][ml]; o.w = L[nl4 + 3][ml];
        *(ushort4*)(y + (size_t)(mb + ml) * 512 + nb + nl4) = o;
    }
}

// ---------------------------------------------------------------------------
template<int S>
__global__ __launch_bounds__(256)
void combine_iter_k(const u16* __restrict__ part, const u16* __restrict__ z0T,
                    u16* __restrict__ zT)
{
    const size_t Sz = (size_t)256 * 8192;
    size_t e = ((size_t)blockIdx.x * 256 + threadIdx.x) * 4;
    ushort4 p0 = *(const ushort4*)(part + e);
    float ax = bf2f(p0.x), ay = bf2f(p0.y), az = bf2f(p0.z), aw = bf2f(p0.w);
#pragma unroll
    for (int s = 1; s < S; ++s) {
        ushort4 v = *(const ushort4*)(part + (size_t)s * Sz + e);
        ax += bf2f(v.x); ay += bf2f(v.y); az += bf2f(v.z); aw += bf2f(v.w);
    }
    ushort4 z0 = *(const ushort4*)(z0T + e);
    ushort4 o;
    o.x = f2bf(0.9f * ax + 0.1f * bf2f(z0.x));
    o.y = f2bf(0.9f * ay + 0.1f * bf2f(z0.y));
    o.z = f2bf(0.9f * az + 0.1f * bf2f(z0.z));
    o.w = f2bf(0.9f * aw + 0.1f * bf2f(z0.w));
    *(ushort4*)(zT + e) = o;
}

// ---------------------------------------------------------------------------
__global__ __launch_bounds__(256)
void softmax_k(const u16* __restrict__ zT, float* __restrict__ out)
{
    __shared__ u16 L[64][260];
    const int t = threadIdx.x;
    const int m0 = blockIdx.x * 64;
    const int tx = t & 15, ty = t >> 4;
#pragma unroll
    for (int i = 0; i < 16; ++i) {
        int n = i * 16 + ty;
        ushort4 v = *(const ushort4*)(zT + (size_t)n * 8192 + m0 + tx * 4);
        L[tx * 4 + 0][n] = v.x; L[tx * 4 + 1][n] = v.y;
        L[tx * 4 + 2][n] = v.z; L[tx * 4 + 3][n] = v.w;
    }
    __syncthreads();
    const int wid = t >> 6, lane = t & 63;
    for (int r = 0; r < 16; ++r) {
        int mm = wid * 16 + r;
        ushort4 u = *(const ushort4*)(&L[mm][lane * 4]);
        float f0 = bf2f(u.x), f1 = bf2f(u.y), f2 = bf2f(u.z), f3 = bf2f(u.w);
        float mx = fmaxf(fmaxf(f0, f1), fmaxf(f2, f3));
#pragma unroll
        for (int off = 32; off > 0; off >>= 1) mx = fmaxf(mx, __shfl_xor(mx, off));
        float e0 = __expf(f0 - mx), e1 = __expf(f1 - mx);
        float e2 = __expf(f2 - mx), e3 = __expf(f3 - mx);
        float s = e0 + e1 + e2 + e3;
#pragma unroll
        for (int off = 32; off > 0; off >>= 1) s += __shfl_xor(s, off);
        float inv = 1.0f / s;
        float4 o;
        o.x = e0 * inv; o.y = e1 * inv; o.z = e2 * inv; o.w = e3 * inv;
        *(float4*)(out + (size_t)(m0 + mm) * 256 + lane * 4) = o;
    }
}

// ---------------------------------------------------------------------------
extern "C" void kernel_launch(void* const* d_in, const int* in_sizes, int n_in,
                              void* d_out, int out_size, void* d_ws, size_t ws_size,
                              hipStream_t stream)
{
    const float* features = (const float*)d_in[0];   // [8192][512]
    const float* fltr     = (const float*)d_in[1];   // [8192][8192]
    const float* W0       = (const float*)d_in[2];   // [512][512]
    const float* b0       = (const float*)d_in[3];   // [512]
    const float* W1       = (const float*)d_in[4];   // [512][512]
    const float* b1       = (const float*)d_in[5];   // [512]
    const float* Wo       = (const float*)d_in[6];   // [512][256]
    const float* bo       = (const float*)d_in[7];   // [256]

    dim3 tb(32, 8);

    // ---- base ws layout (~71 MB; part bf16) ----
    char* p = (char*)d_ws;
    u16* fB  = (u16*)p;  p += (size_t)8192 * 512 * 2;
    u16* W0T = (u16*)p;  p += (size_t)512 * 512 * 2;
    u16* W1T = (u16*)p;  p += (size_t)512 * 512 * 2;
    u16* WoT = (u16*)p;  p += (size_t)256 * 512 * 2;
    u16* z0T = (u16*)p;  p += (size_t)256 * 8192 * 2;
    u16* zA  = (u16*)p;  p += (size_t)256 * 8192 * 2;
    u16* zB  = (u16*)p;  p += (size_t)256 * 8192 * 2;
    u16* tT  = (u16*)p;  p += (size_t)512 * 8192 * 2;
    u16* y   = (u16*)p;  p += (size_t)8192 * 512 * 2;
    u16* part = (u16*)p; p += (size_t)4 * 512 * 8192 * 2;   // 33.6 MB (= 8*256*8192*2)
    size_t base_need = (size_t)(p - (char*)d_ws);
    u16* fltrB = (u16*)p;                             // +134.2 MB (full tier)
    size_t full_need = base_need + (size_t)8192 * 8192 * 2;

    if (ws_size >= full_need) {
        // ================= FULL TIER =================
        cvt_f2b_k<<<2048, 256, 0, stream>>>(fltr, fltrB, (long)8192 * 8192 / 4);
        cvt_f2b_k<<<512, 256, 0, stream>>>(features, fB, (long)8192 * 512 / 4);
        transpose_cvt_k<<<dim3(16, 16), tb, 0, stream>>>(W0, W0T, 512, 512);
        transpose_cvt_k<<<dim3(16, 16), tb, 0, stream>>>(W1, W1T, 512, 512);
        transpose_cvt_k<<<dim3(8, 16),  tb, 0, stream>>>(Wo, WoT, 512, 256);

        // t0 = (features @ W0 + b0)^T  — direct, sk=1, 256 blocks
        gemm_bt<0, 0><<<dim3(64, 4, 1), 256, 0, stream>>>(fB, 512, W0T, 512, 8,
                                                          tT, b0, 8192, 0);
        // y1 = relu(fltr @ t0) — 256^2 4-phase, sk=4, 256 blocks, nt=32
        gemm256<<<dim3(32, 2, 4), 512, 0, stream>>>(fltrB, 8192, tT, 8192, 32,
                                                    part, 512);
        combine_mlp_k<4><<<dim3(128, 8), 256, 0, stream>>>(part, y);
        // t1 = (y1 @ W1 + b1)^T     — direct, sk=1
        gemm_bt<0, 0><<<dim3(64, 4, 1), 256, 0, stream>>>(y, 512, W1T, 512, 8,
                                                          tT, b1, 8192, 0);
        // y2 = relu(fltr @ t1)
        gemm256<<<dim3(32, 2, 4), 512, 0, stream>>>(fltrB, 8192, tT, 8192, 32,
                                                    part, 512);
        combine_mlp_k<4><<<dim3(128, 8), 256, 0, stream>>>(part, y);
        // z0 = (y2 @ Wo + bo)^T     — direct, sk=1, 128 blocks
        gemm_bt<0, 0><<<dim3(64, 2, 1), 256, 0, stream>>>(y, 512, WoT, 512, 8,
                                                          z0T, bo, 8192, 0);
        // 10x: z <- 0.9*fltr@z + 0.1*z0 — 256^2 4-phase, sk=8, 256 blocks, nt=16
        const u16* src = z0T;
        for (int it = 0; it < 10; ++it) {
            u16* dst = (it & 1) ? zB : zA;
            gemm256<<<dim3(32, 1, 8), 512, 0, stream>>>(fltrB, 8192, src, 8192,
                                                        16, part, 256);
            combine_iter_k<8><<<2048, 256, 0, stream>>>(part, z0T, dst);
            src = dst;
        }
        softmax_k<<<128, 256, 0, stream>>>(src, (float*)d_out);
    } else if (ws_size >= base_need) {
        // ================= MIDDLE TIER (fltr stays fp32) =================
        cvt_f2b_k<<<512, 256, 0, stream>>>(features, fB, (long)8192 * 512 / 4);
        transpose_cvt_k<<<dim3(16, 16), tb, 0, stream>>>(W0, W0T, 512, 512);
        transpose_cvt_k<<<dim3(16, 16), tb, 0, stream>>>(W1, W1T, 512, 512);
        transpose_cvt_k<<<dim3(8, 16),  tb, 0, stream>>>(Wo, WoT, 512, 256);

        gemm_bt<2, 0><<<dim3(64, 4, 2), 256, 0, stream>>>(fB, 512, W0T, 512, 4,
                                                          part, nullptr, 0, 512);
        combine_bias_k<2><<<4096, 256, 0, stream>>>(part, b0, tT, 512);
        gemm_bt<2, 1><<<dim3(64, 4, 4), 256, 0, stream>>>(fltr, 8192, tT, 8192,
                                                          32, part, nullptr, 0, 512);
        combine_mlp_k<4><<<dim3(128, 8), 256, 0, stream>>>(part, y);
        gemm_bt<2, 0><<<dim3(64, 4, 2), 256, 0, stream>>>(y, 512, W1T, 512, 4,
                                                          part, nullptr, 0, 512);
        combine_bias_k<2><<<4096, 256, 0, stream>>>(part, b1, tT, 512);
        gemm_bt<2, 1><<<dim3(64, 4, 4), 256, 0, stream>>>(fltr, 8192, tT, 8192,
                                                          32, part, nullptr, 0, 512);
        combine_mlp_k<4><<<dim3(128, 8), 256, 0, stream>>>(part, y);
        gemm_bt<2, 0><<<dim3(64, 2, 4), 256, 0, stream>>>(y, 512, WoT, 512, 2,
                                                          part, nullptr, 0, 256);
        combine_bias_k<4><<<2048, 256, 0, stream>>>(part, bo, z0T, 256);
        const u16* src = z0T;
        for (int it = 0; it < 10; ++it) {
            u16* dst = (it & 1) ? zB : zA;
            gemm_bt<2, 1><<<dim3(64, 2, 8), 256, 0, stream>>>(fltr, 8192, src,
                                                              8192, 16, part,
                                                              nullptr, 0, 256);
            combine_iter_k<8><<<2048, 256, 0, stream>>>(part, z0T, dst);
            src = dst;
        }
        softmax_k<<<128, 256, 0, stream>>>(src, (float*)d_out);
    } else {
        // ================= FALLBACK (21.25 MB) =================
        char* w = (char*)d_ws;
        u16* fW0T = (u16*)w;  w += (size_t)512 * 512 * 2;
        u16* fW1T = (u16*)w;  w += (size_t)512 * 512 * 2;
        u16* fWoT = (u16*)w;  w += (size_t)256 * 512 * 2;
        u16* fz0T = (u16*)w;  w += (size_t)256 * 8192 * 2;
        char* rb = w;
        u16* ftT = (u16*)rb;
        u16* fy  = (u16*)(rb + (size_t)512 * 8192 * 2);
        u16* fzA = (u16*)rb;
        u16* fzB = (u16*)(rb + (size_t)256 * 8192 * 2);

        transpose_cvt_k<<<dim3(16, 16), tb, 0, stream>>>(W0, fW0T, 512, 512);
        transpose_cvt_k<<<dim3(16, 16), tb, 0, stream>>>(W1, fW1T, 512, 512);
        transpose_cvt_k<<<dim3(8, 16),  tb, 0, stream>>>(Wo, fWoT, 512, 256);
        gemm_bt<0, 1><<<dim3(64, 4), 256, 0, stream>>>(features, 512, fW0T, 512, 8,
                                                       ftT, b0, 8192, 0);
        gemm_bt<1, 1><<<dim3(64, 4), 256, 0, stream>>>(fltr, 8192, ftT, 8192, 128,
                                                       fy, nullptr, 512, 0);
        gemm_bt<0, 0><<<dim3(64, 4), 256, 0, stream>>>(fy, 512, fW1T, 512, 8,
                                                       ftT, b1, 8192, 0);
        gemm_bt<1, 1><<<dim3(64, 4), 256, 0, stream>>>(fltr, 8192, ftT, 8192, 128,
                                                       fy, nullptr, 512, 0);
        gemm_bt<0, 0><<<dim3(64, 2), 256, 0, stream>>>(fy, 512, fWoT, 512, 8,
                                                       fz0T, bo, 8192, 0);
        const u16* src = fz0T;
        for (int it = 0; it < 10; ++it) {
            u16* dst = (it & 1) ? fzB : fzA;
            gemm_bt<3, 1><<<dim3(64, 2), 256, 0, stream>>>(fltr, 8192, src, 8192,
                                                           128, dst, fz0T, 8192, 0);
            src = dst;
        }
        softmax_k<<<128, 256, 0, stream>>>(src, (float*)d_out);
    }
}